// Round 1
// baseline (846.110 us; speedup 1.0000x reference)
//
#include <hip/hip_runtime.h>
#include <hip/hip_bf16.h>

#define M_ROWS 12000
#define K_DIM  12000
#define FEAT   256
#define NCLS   40
#define STEPS_TOTAL 375   // 12000 / 32

typedef __attribute__((ext_vector_type(4))) float f32x4;
typedef __attribute__((ext_vector_type(8))) short s16x8;

__device__ __forceinline__ short f2bf(float f){
  __hip_bfloat16 h = __float2bfloat16(f);
  union { __hip_bfloat16 h; short s; } u; u.h = h; return u.s;
}

__device__ __forceinline__ f32x4 mfma16(s16x8 a, s16x8 b, f32x4 c){
  return __builtin_amdgcn_mfma_f32_16x16x32_bf16(a, b, c, 0, 0, 0);
}

// ---------------------------------------------------------------------------
// fp32 [12000][256]  ->  bf16 [256][12000]  (transposed, K-contiguous rows)
// ---------------------------------------------------------------------------
__global__ __launch_bounds__(256) void k_transpose_bf16(const float* __restrict__ src,
                                                        short* __restrict__ dst){
  __shared__ float tile[32][257];
  const int t  = threadIdx.x;
  const int r0 = blockIdx.x * 32;
  {
    const int r = t >> 3, cs = (t & 7) * 32;
    const float* s = src + (size_t)(r0 + r) * FEAT + cs;
    #pragma unroll
    for (int i = 0; i < 8; ++i){
      f32x4 v = *(const f32x4*)(s + 4*i);
      tile[r][cs + 4*i + 0] = v[0];
      tile[r][cs + 4*i + 1] = v[1];
      tile[r][cs + 4*i + 2] = v[2];
      tile[r][cs + 4*i + 3] = v[3];
    }
  }
  __syncthreads();
  const int c = t;
  short* d = dst + (size_t)c * M_ROWS + r0;
  #pragma unroll
  for (int i = 0; i < 4; ++i){
    s16x8 o;
    #pragma unroll
    for (int j = 0; j < 8; ++j) o[j] = f2bf(tile[8*i + j][c]);
    *(s16x8*)(d + 8*i) = o;
  }
}

// ---------------------------------------------------------------------------
// Big GEMM: P[s] = adj[:, kslice] @ B[kslice, :]   (bf16 MFMA, fp32 accum)
// BM=96 (125 tiles), BN=256, BK=32, 4 waves, wave tile 96x64 (M_rep=6,N_rep=4)
// ---------------------------------------------------------------------------
__global__ __launch_bounds__(256) void k_gemm(const float* __restrict__ adj,
                                              const short* __restrict__ BT,
                                              float* __restrict__ Pbase, int S){
  __shared__ short Alds[96 * 32];    // [row][slot^swz(row)][8]
  __shared__ short Blds[256 * 32];   // [col][slot^swz(col)][8]

  const int t  = threadIdx.x;
  const int bm = blockIdx.x;
  const int s  = blockIdx.y;
  const int per = STEPS_TOTAL / S, rem = STEPS_TOTAL % S;
  const int st0 = s * per + (s < rem ? s : rem);
  const int nst = per + (s < rem ? 1 : 0);

  const int l  = t & 63, w = t >> 6;
  const int lr = l & 15, lg = l >> 4;
  const int fswz = (lr >> 1) & 3;

  f32x4 acc[6][4];
  #pragma unroll
  for (int m = 0; m < 6; ++m)
    #pragma unroll
    for (int j = 0; j < 4; ++j) acc[m][j] = (f32x4)(0.0f);

  // staging roles
  const int ar = t >> 1, ah = t & 1;                       // A: t<192, row ar, half ah
  const float* aptr = adj + (size_t)(bm * 96 + ar) * K_DIM + ah * 16;
  const int aswz = (ar >> 1) & 3;
  const short* bptr = BT + (size_t)t * K_DIM;              // B: col t
  const int bswz = (t >> 1) & 3;

  for (int stp = 0; stp < nst; ++stp){
    const int kk = (st0 + stp) * 32;

    // global loads
    s16x8 bv[4];
    #pragma unroll
    for (int i = 0; i < 4; ++i) bv[i] = *(const s16x8*)(bptr + kk + 8*i);

    s16x8 av0, av1;
    if (t < 192){
      const float* ap = aptr + kk;
      f32x4 f0 = *(const f32x4*)(ap + 0);
      f32x4 f1 = *(const f32x4*)(ap + 4);
      f32x4 f2 = *(const f32x4*)(ap + 8);
      f32x4 f3 = *(const f32x4*)(ap + 12);
      #pragma unroll
      for (int j = 0; j < 4; ++j){ av0[j] = f2bf(f0[j]); av0[4+j] = f2bf(f1[j]); }
      #pragma unroll
      for (int j = 0; j < 4; ++j){ av1[j] = f2bf(f2[j]); av1[4+j] = f2bf(f3[j]); }
    }

    // LDS writes (swizzled 16B slots)
    #pragma unroll
    for (int i = 0; i < 4; ++i)
      *(s16x8*)(&Blds[t * 32 + ((i ^ bswz) * 8)]) = bv[i];
    if (t < 192){
      *(s16x8*)(&Alds[ar * 32 + (((2*ah    ) ^ aswz) * 8)]) = av0;
      *(s16x8*)(&Alds[ar * 32 + (((2*ah + 1) ^ aswz) * 8)]) = av1;
    }
    __syncthreads();

    // fragments
    s16x8 af[6], bf[4];
    #pragma unroll
    for (int m = 0; m < 6; ++m)
      af[m] = *(const s16x8*)(&Alds[(16*m + lr) * 32 + ((lg ^ fswz) * 8)]);
    #pragma unroll
    for (int j = 0; j < 4; ++j)
      bf[j] = *(const s16x8*)(&Blds[(w*64 + j*16 + lr) * 32 + ((lg ^ fswz) * 8)]);

    #pragma unroll
    for (int m = 0; m < 6; ++m)
      #pragma unroll
      for (int j = 0; j < 4; ++j)
        acc[m][j] = mfma16(af[m], bf[j], acc[m][j]);
    __syncthreads();
  }

  // epilogue: C/D layout col=lane&15, row=(lane>>4)*4+reg
  float* P = Pbase + (size_t)s * M_ROWS * FEAT;
  #pragma unroll
  for (int m = 0; m < 6; ++m){
    const int row = bm * 96 + 16*m + lg * 4;
    #pragma unroll
    for (int j = 0; j < 4; ++j){
      const int col = w*64 + j*16 + lr;
      float* p = P + (size_t)row * FEAT + col;
      #pragma unroll
      for (int r = 0; r < 4; ++r) p[(size_t)r * FEAT] = acc[m][j][r];
    }
  }
}

// ---------------------------------------------------------------------------
// P[0] += P[1..S-1]
// ---------------------------------------------------------------------------
__global__ void k_reduce(float* __restrict__ Pbase, int S){
  const size_t n = (size_t)M_ROWS * FEAT / 4;
  const size_t stride = (size_t)gridDim.x * blockDim.x;
  f32x4* P0 = (f32x4*)Pbase;
  for (size_t i = (size_t)blockIdx.x * blockDim.x + threadIdx.x; i < n; i += stride){
    f32x4 v = P0[i];
    for (int s = 1; s < S; ++s)
      v += ((const f32x4*)(Pbase + (size_t)s * M_ROWS * FEAT))[i];
    P0[i] = v;
  }
}

// ---------------------------------------------------------------------------
// H = l2norm_rows(relu(Y @ W + b))   fp32; block = 32 rows, thread = 4x8 tile
// ---------------------------------------------------------------------------
__global__ __launch_bounds__(256) void k_fused(const float* __restrict__ Y,
                                               const float* __restrict__ W,
                                               const float* __restrict__ b,
                                               float* __restrict__ H){
  __shared__ float ylds[32][257];
  __shared__ float red[32][33];
  __shared__ float scale[32];
  const int t  = threadIdx.x;
  const int r0 = blockIdx.x * 32;
  {
    const int r = t >> 3, cs = (t & 7) * 32;
    const float* yp = Y + (size_t)(r0 + r) * FEAT + cs;
    #pragma unroll
    for (int i = 0; i < 8; ++i){
      f32x4 v = *(const f32x4*)(yp + 4*i);
      ylds[r][cs + 4*i + 0] = v[0];
      ylds[r][cs + 4*i + 1] = v[1];
      ylds[r][cs + 4*i + 2] = v[2];
      ylds[r][cs + 4*i + 3] = v[3];
    }
  }
  __syncthreads();

  const int rg = t >> 5;   // row group: rows rg*4 .. rg*4+3
  const int cg = t & 31;   // col group: cols cg*8 .. cg*8+7
  float acc[4][8];
  {
    float bias[8];
    #pragma unroll
    for (int j = 0; j < 8; ++j) bias[j] = b[cg*8 + j];
    #pragma unroll
    for (int i = 0; i < 4; ++i)
      #pragma unroll
      for (int j = 0; j < 8; ++j) acc[i][j] = bias[j];
  }

  #pragma unroll 4
  for (int k = 0; k < FEAT; ++k){
    float yv[4];
    #pragma unroll
    for (int i = 0; i < 4; ++i) yv[i] = ylds[rg*4 + i][k];
    f32x4 w0 = *(const f32x4*)(W + (size_t)k * FEAT + cg*8);
    f32x4 w1 = *(const f32x4*)(W + (size_t)k * FEAT + cg*8 + 4);
    #pragma unroll
    for (int i = 0; i < 4; ++i){
      #pragma unroll
      for (int j = 0; j < 4; ++j){
        acc[i][j]     += yv[i] * w0[j];
        acc[i][4 + j] += yv[i] * w1[j];
      }
    }
  }

  // relu + row sum of squares
  #pragma unroll
  for (int i = 0; i < 4; ++i){
    float ss = 0.0f;
    #pragma unroll
    for (int j = 0; j < 8; ++j){
      float v = fmaxf(acc[i][j], 0.0f);
      acc[i][j] = v;
      ss += v * v;
    }
    red[rg*4 + i][cg] = ss;
  }
  __syncthreads();
  if (t < 32){
    float ssum = 0.0f;
    #pragma unroll
    for (int j = 0; j < 32; ++j) ssum += red[t][j];
    float nrm = sqrtf(ssum);
    scale[t] = 1.0f / fmaxf(nrm, 1e-12f);
  }
  __syncthreads();

  #pragma unroll
  for (int i = 0; i < 4; ++i){
    const float sc = scale[rg*4 + i];
    f32x4 o0, o1;
    #pragma unroll
    for (int j = 0; j < 4; ++j){ o0[j] = acc[i][j] * sc; o1[j] = acc[i][4 + j] * sc; }
    float* hp = H + (size_t)(r0 + rg*4 + i) * FEAT + cg*8;
    *(f32x4*)(hp)     = o0;
    *(f32x4*)(hp + 4) = o1;
  }
}

// ---------------------------------------------------------------------------
// out = Y @ W2 + b2    (12000 x 40), thread per output element
// ---------------------------------------------------------------------------
__global__ __launch_bounds__(256) void k_final(const float* __restrict__ Y,
                                               const float* __restrict__ W2,
                                               const float* __restrict__ b2,
                                               float* __restrict__ out){
  const int idx = blockIdx.x * 256 + threadIdx.x;
  if (idx >= M_ROWS * NCLS) return;
  const int m = idx / NCLS, n = idx % NCLS;
  const float* y = Y + (size_t)m * FEAT;
  float a = b2[n];
  #pragma unroll 4
  for (int k = 0; k < FEAT; ++k)
    a = fmaf(y[k], W2[(size_t)k * NCLS + n], a);
  out[idx] = a;
}

// ---------------------------------------------------------------------------
extern "C" void kernel_launch(void* const* d_in, const int* in_sizes, int n_in,
                              void* d_out, int out_size, void* d_ws, size_t ws_size,
                              hipStream_t stream){
  const float* adj = (const float*)d_in[0];
  const float* x   = (const float*)d_in[1];
  const float* W0  = (const float*)d_in[2];
  const float* b0  = (const float*)d_in[3];
  const float* W1  = (const float*)d_in[4];
  const float* b1  = (const float*)d_in[5];
  const float* W2  = (const float*)d_in[6];
  const float* b2  = (const float*)d_in[7];
  float* out = (float*)d_out;

  char* ws = (char*)d_ws;
  const size_t HBT_BYTES = (size_t)FEAT * M_ROWS * 2;   //  6,144,000
  const size_t SLAB      = (size_t)M_ROWS * FEAT * 4;   // 12,288,000

  short* HbT = (short*)ws;
  float* P   = (float*)(ws + HBT_BYTES);

  int slabs = (ws_size > HBT_BYTES) ? (int)((ws_size - HBT_BYTES) / SLAB) : 2;
  int S = slabs - 1;            // last slab is H
  if (S > 6) S = 6;
  if (S < 1) S = 1;
  float* H = P + (size_t)S * (SLAB / 4);
  float* Y = P;                 // after reduce, slab 0 holds the full sum

  const dim3 b256(256);

  k_transpose_bf16<<<375, b256, 0, stream>>>(x, HbT);

  for (int layer = 0; layer < 3; ++layer){
    k_gemm<<<dim3(125, S), b256, 0, stream>>>(adj, HbT, P, S);
    if (S > 1) k_reduce<<<1024, b256, 0, stream>>>(P, S);
    if (layer == 0){
      k_fused<<<375, b256, 0, stream>>>(Y, W0, b0, H);
      k_transpose_bf16<<<375, b256, 0, stream>>>(H, HbT);
    } else if (layer == 1){
      k_fused<<<375, b256, 0, stream>>>(Y, W1, b1, H);
      k_transpose_bf16<<<375, b256, 0, stream>>>(H, HbT);
    } else {
      k_final<<<1875, b256, 0, stream>>>(Y, W2, b2, out);
    }
  }
}